// Round 1
// 26998.450 us; speedup vs baseline: 1.0382x; 1.0382x over previous
//
#include <hip/hip_runtime.h>
#include <math.h>

#define LSTR 36  // LDS row stride in floats (144B: 16B-aligned, conflict-benign)

// ---------------------------------------------------------------------------
// Generic 32(M-rows) x 64(N-cols) tile GEMM core: C = act(A @ W^T + b1 + b2)
// A: [rows x K] row-major (lda), W: [N x K] row-major (ldw). 128 threads.
// Thread (jl = tid&15, bg = tid>>4) owns 4x4 outputs:
//   n = n0 + jl + 16*jn, b = bg + 8*jb
// K-loop is register-staged double-buffered: tile kk+32 is fetched into
// registers while tile kk computes (hides global/L3 latency, T14 pattern).
// ---------------------------------------------------------------------------
__device__ __forceinline__ void gemm_core(
    const float* __restrict__ A, int lda,
    const float* __restrict__ W, int ldw,
    int n0, int N, int K,
    const float* __restrict__ b1, const float* __restrict__ b2,
    int act, float* __restrict__ C, int ldc, int row0,
    float* As, float* Ws)
{
    const int tid = threadIdx.x;
    const int jl = tid & 15;
    const int bg = tid >> 4;
    float acc[4][4] = {{0.f,0.f,0.f,0.f},{0.f,0.f,0.f,0.f},{0.f,0.f,0.f,0.f},{0.f,0.f,0.f,0.f}};

    // staging registers (double buffer)
    float4 ra[2], rw[4];

    // per-thread staging coordinates (constant across kk)
    int ar[2], akv[2], wr[4], wkv[4];
#pragma unroll
    for (int p = 0; p < 2; ++p) {
        int i = tid + 128 * p;
        ar[p] = i >> 3; akv[p] = (i & 7) << 2;
    }
#pragma unroll
    for (int p = 0; p < 4; ++p) {
        int i = tid + 128 * p;
        wr[p] = i >> 3; wkv[p] = (i & 7) << 2;
    }

    // prefetch tile 0
#pragma unroll
    for (int p = 0; p < 2; ++p)
        ra[p] = *(const float4*)(A + (size_t)(row0 + ar[p]) * lda + akv[p]);
#pragma unroll
    for (int p = 0; p < 4; ++p) {
        int n = n0 + wr[p];
        rw[p] = (n < N) ? *(const float4*)(W + (size_t)n * ldw + wkv[p])
                        : make_float4(0.f, 0.f, 0.f, 0.f);
    }

    for (int kk = 0; kk < K; kk += 32) {
        // write current regs -> LDS (compiler inserts vmcnt wait)
#pragma unroll
        for (int p = 0; p < 2; ++p)
            *(float4*)&As[ar[p] * LSTR + akv[p]] = ra[p];
#pragma unroll
        for (int p = 0; p < 4; ++p)
            *(float4*)&Ws[wr[p] * LSTR + wkv[p]] = rw[p];
        __syncthreads();

        // issue next tile's global loads (latency hides under compute)
        if (kk + 32 < K) {
            int kn = kk + 32;
#pragma unroll
            for (int p = 0; p < 2; ++p)
                ra[p] = *(const float4*)(A + (size_t)(row0 + ar[p]) * lda + kn + akv[p]);
#pragma unroll
            for (int p = 0; p < 4; ++p) {
                int n = n0 + wr[p];
                rw[p] = (n < N) ? *(const float4*)(W + (size_t)n * ldw + kn + wkv[p])
                                : make_float4(0.f, 0.f, 0.f, 0.f);
            }
        }

#pragma unroll
        for (int k4 = 0; k4 < 8; ++k4) {
            float4 av[4], wv[4];
#pragma unroll
            for (int jb = 0; jb < 4; ++jb) av[jb] = *(float4*)&As[(bg + 8 * jb) * LSTR + k4 * 4];
#pragma unroll
            for (int jn = 0; jn < 4; ++jn) wv[jn] = *(float4*)&Ws[(jl + 16 * jn) * LSTR + k4 * 4];
#pragma unroll
            for (int jn = 0; jn < 4; ++jn)
#pragma unroll
                for (int jb = 0; jb < 4; ++jb) {
                    acc[jn][jb] += av[jb].x * wv[jn].x;
                    acc[jn][jb] += av[jb].y * wv[jn].y;
                    acc[jn][jb] += av[jb].z * wv[jn].z;
                    acc[jn][jb] += av[jb].w * wv[jn].w;
                }
        }
        __syncthreads();
    }

#pragma unroll
    for (int jn = 0; jn < 4; ++jn) {
        int n = n0 + jl + 16 * jn;
        if (n < N) {
            float bb = (b1 ? b1[n] : 0.f) + (b2 ? b2[n] : 0.f);
#pragma unroll
            for (int jb = 0; jb < 4; ++jb) {
                int b = bg + 8 * jb;
                float x = acc[jn][jb] + bb;
                if (act == 1) x = tanhf(x);
                C[(size_t)(row0 + b) * ldc + n] = x;
            }
        }
    }
}

__global__ void __launch_bounds__(128) gemm_generic(
    const float* __restrict__ A, int lda, const float* __restrict__ W, int ldw,
    const float* __restrict__ b1, const float* __restrict__ b2,
    float* __restrict__ C, int ldc, int N, int K, int act, int swapxy)
{
    __shared__ __align__(16) float As[32 * LSTR];
    __shared__ __align__(16) float Ws[64 * LSTR];
    int bn = swapxy ? blockIdx.y : blockIdx.x;
    int bm = swapxy ? blockIdx.x : blockIdx.y;
    gemm_core(A, lda, W, ldw, bn * 64, N, K, b1, b2, act, C, ldc, bm * 32, As, Ws);
}

// ---------------------------------------------------------------------------
// step_pre: everything that depends only on t-1 state, in one launch.
//  seg0 (blk 0..15):   u     = tanh(w2p_W @ h_w1(t-1) + w2p_b)        N=1024 K=1024
//  seg1 (blk 16..31):  hp_hh = p_Whh0 @ h_p(t-1)                      N=1024 K=256
//  seg2 (blk 32..95):  w0_hh = w_Whh0 @ h_w0(t-1)                     N=4096 K=1024
//  seg3 (blk 96..159): w1_hh = w_Whh1 @ h_w1(t-1) + bih1 + bhh1       N=4096 K=1024
// ---------------------------------------------------------------------------
__global__ void __launch_bounds__(128) step_pre(
    int t, const float* __restrict__ Hw1, const float* __restrict__ Hp,
    const float* __restrict__ h_w0,
    const float* __restrict__ w2p_W, const float* __restrict__ w2p_b,
    const float* __restrict__ p_Whh0,
    const float* __restrict__ w_Whh0, const float* __restrict__ w_Whh1,
    const float* __restrict__ w_bih1, const float* __restrict__ w_bhh1,
    float* __restrict__ u, float* __restrict__ hp_hh,
    float* __restrict__ w0_hh, float* __restrict__ w1_hh)
{
    __shared__ __align__(16) float As[32 * LSTR];
    __shared__ __align__(16) float Ws[64 * LSTR];
    int blk = blockIdx.x;
    const float* hw1 = Hw1 + (size_t)t * 32 * 1024;  // h_w1(t-1)
    const float* hp  = Hp  + (size_t)t * 32 * 256;   // h_p(t-1)
    if (blk < 16)
        gemm_core(hw1, 1024, w2p_W, 1024, blk * 64, 1024, 1024, w2p_b, nullptr, 1, u, 1024, 0, As, Ws);
    else if (blk < 32)
        gemm_core(hp, 256, p_Whh0, 256, (blk - 16) * 64, 1024, 256, nullptr, nullptr, 0, hp_hh, 1024, 0, As, Ws);
    else if (blk < 96)
        gemm_core(h_w0, 1024, w_Whh0, 1024, (blk - 32) * 64, 4096, 1024, nullptr, nullptr, 0, w0_hh, 4096, 0, As, Ws);
    else
        gemm_core(hw1, 1024, w_Whh1, 1024, (blk - 96) * 64, 4096, 1024, w_bih1, w_bhh1, 0, w1_hh, 4096, 0, As, Ws);
}

// ---------------------------------------------------------------------------
// LSTM cell: block handles 16 hidden units x 4 gates (64 W-rows) x 32 batch.
// gates = A @ Wih_part^T + addA + addB   (biases pre-folded into addends)
// Thread's 4 n-values are exactly gates i,f,g,o for hidden j = j0 + (tid&15).
// Same register-staged double-buffered K-loop as gemm_core.
// ---------------------------------------------------------------------------
__global__ void __launch_bounds__(128) lstm_cell(
    const float* __restrict__ A, int K,
    const float* __restrict__ Wih, int ldw, int H,
    const float* __restrict__ addA, int ldA,
    const float* __restrict__ addB, int ldB,
    float* __restrict__ h_out, float* __restrict__ c_state)
{
    __shared__ __align__(16) float As[32 * LSTR];
    __shared__ __align__(16) float Ws[64 * LSTR];
    const int tid = threadIdx.x;
    const int jl = tid & 15;
    const int bg = tid >> 4;
    const int j0 = blockIdx.x * 16;
    float acc[4][4] = {{0.f,0.f,0.f,0.f},{0.f,0.f,0.f,0.f},{0.f,0.f,0.f,0.f},{0.f,0.f,0.f,0.f}};

    float4 ra[2], rw[4];
    int ar[2], akv[2], wr[4], wkv[4], wrow[4];
#pragma unroll
    for (int p = 0; p < 2; ++p) {
        int i = tid + 128 * p;
        ar[p] = i >> 3; akv[p] = (i & 7) << 2;
    }
#pragma unroll
    for (int p = 0; p < 4; ++p) {
        int i = tid + 128 * p;
        wr[p] = i >> 3; wkv[p] = (i & 7) << 2;
        wrow[p] = (wr[p] >> 4) * H + j0 + (wr[p] & 15);  // gate-grouped row
    }

    // prefetch tile 0
#pragma unroll
    for (int p = 0; p < 2; ++p)
        ra[p] = *(const float4*)(A + (size_t)ar[p] * K + akv[p]);
#pragma unroll
    for (int p = 0; p < 4; ++p)
        rw[p] = *(const float4*)(Wih + (size_t)wrow[p] * ldw + wkv[p]);

    for (int kk = 0; kk < K; kk += 32) {
#pragma unroll
        for (int p = 0; p < 2; ++p)
            *(float4*)&As[ar[p] * LSTR + akv[p]] = ra[p];
#pragma unroll
        for (int p = 0; p < 4; ++p)
            *(float4*)&Ws[wr[p] * LSTR + wkv[p]] = rw[p];
        __syncthreads();

        if (kk + 32 < K) {
            int kn = kk + 32;
#pragma unroll
            for (int p = 0; p < 2; ++p)
                ra[p] = *(const float4*)(A + (size_t)ar[p] * K + kn + akv[p]);
#pragma unroll
            for (int p = 0; p < 4; ++p)
                rw[p] = *(const float4*)(Wih + (size_t)wrow[p] * ldw + kn + wkv[p]);
        }

#pragma unroll
        for (int k4 = 0; k4 < 8; ++k4) {
            float4 av[4], wv[4];
#pragma unroll
            for (int jb = 0; jb < 4; ++jb) av[jb] = *(float4*)&As[(bg + 8 * jb) * LSTR + k4 * 4];
#pragma unroll
            for (int jn = 0; jn < 4; ++jn) wv[jn] = *(float4*)&Ws[(jl + 16 * jn) * LSTR + k4 * 4];
#pragma unroll
            for (int jn = 0; jn < 4; ++jn)
#pragma unroll
                for (int jb = 0; jb < 4; ++jb) {
                    acc[jn][jb] += av[jb].x * wv[jn].x;
                    acc[jn][jb] += av[jb].y * wv[jn].y;
                    acc[jn][jb] += av[jb].z * wv[jn].z;
                    acc[jn][jb] += av[jb].w * wv[jn].w;
                }
        }
        __syncthreads();
    }

    const int j = j0 + jl;
#pragma unroll
    for (int jb = 0; jb < 4; ++jb) {
        int b = bg + 8 * jb;
        float g[4];
#pragma unroll
        for (int jn = 0; jn < 4; ++jn) {
            int row = jn * H + j;
            float x = acc[jn][jb];
            if (addA) x += addA[(size_t)b * ldA + row];
            if (addB) x += addB[(size_t)b * ldB + row];
            g[jn] = x;
        }
        float c_old = c_state[b * H + j];
        float ii = 1.f / (1.f + expf(-g[0]));
        float ff = 1.f / (1.f + expf(-g[1]));
        float gg = tanhf(g[2]);
        float oo = 1.f / (1.f + expf(-g[3]));
        float cn = ff * c_old + ii * gg;
        float hn = oo * tanhf(cn);
        c_state[b * H + j] = cn;
        h_out[b * H + j] = hn;
    }
}

// ---------------------------------------------------------------------------
// Embedding gather: row = t*32+b
// ---------------------------------------------------------------------------
__global__ void __launch_bounds__(128) gather_emb(
    const int* __restrict__ pos, const int* __restrict__ word,
    const float* __restrict__ pe, const float* __restrict__ we,
    float* __restrict__ Xp, float* __restrict__ Xw)
{
    int row = blockIdx.x;
    int p = pos[row];
    int w = word[row];
    for (int i = threadIdx.x; i < 128; i += 128)
        Xp[(size_t)row * 128 + i] = pe[(size_t)p * 128 + i];
    for (int i = threadIdx.x; i < 512; i += 128)
        Xw[(size_t)row * 512 + i] = we[(size_t)w * 512 + i];
}

// ---------------------------------------------------------------------------
// POS head: per row (t*32+b), 48 logits from h_p (K=256) + log_softmax.
// One wave per row, lane = vocab idx.
// ---------------------------------------------------------------------------
__global__ void __launch_bounds__(256) pos_out_k(
    const float* __restrict__ Hp, const float* __restrict__ W,
    const float* __restrict__ bias, float* __restrict__ out)
{
    int row = blockIdx.x * 4 + (threadIdx.x >> 6);
    int lane = threadIdx.x & 63;
    const float* h = Hp + (size_t)row * 256;
    float logit = -INFINITY;
    if (lane < 48) {
        float s = bias[lane];
        const float* w = W + (size_t)lane * 256;
        for (int k = 0; k < 256; k += 4) {
            s += h[k] * w[k];
            s += h[k + 1] * w[k + 1];
            s += h[k + 2] * w[k + 2];
            s += h[k + 3] * w[k + 3];
        }
        logit = s;
    }
    float m = logit;
    for (int off = 1; off < 64; off <<= 1) m = fmaxf(m, __shfl_xor(m, off));
    float e = (lane < 48) ? expf(logit - m) : 0.f;
    float ssum = e;
    for (int off = 1; off < 64; off <<= 1) ssum += __shfl_xor(ssum, off);
    float ls = m + logf(ssum);
    if (lane < 48) out[(size_t)row * 48 + lane] = logit - ls;
}

// ---------------------------------------------------------------------------
// In-place log_softmax over 32000: online max+sum pass, then subtract pass.
// (2 passes instead of 3; float4 loads; row stays L2-hot after pass 1)
// ---------------------------------------------------------------------------
__global__ void __launch_bounds__(256) logsoftmax_w(float* __restrict__ out)
{
    __shared__ float redm[256], reds[256];
    int row = blockIdx.x;
    float* p = out + (size_t)row * 32000;
    float4* p4 = (float4*)p;
    int tid = threadIdx.x;

    float m = -INFINITY, s = 0.f;
    for (int i = tid; i < 8000; i += 256) {
        float4 v = p4[i];
        float x;
        x = v.x; if (x > m) { s = s * expf(m - x) + 1.f; m = x; } else s += expf(x - m);
        x = v.y; if (x > m) { s = s * expf(m - x) + 1.f; m = x; } else s += expf(x - m);
        x = v.z; if (x > m) { s = s * expf(m - x) + 1.f; m = x; } else s += expf(x - m);
        x = v.w; if (x > m) { s = s * expf(m - x) + 1.f; m = x; } else s += expf(x - m);
    }
    redm[tid] = m; reds[tid] = s;
    __syncthreads();
    for (int st = 128; st > 0; st >>= 1) {
        if (tid < st) {
            float m2 = redm[tid + st], s2 = reds[tid + st];
            float M = fmaxf(redm[tid], m2);
            reds[tid] = reds[tid] * expf(redm[tid] - M) + s2 * expf(m2 - M);
            redm[tid] = M;
        }
        __syncthreads();
    }
    float ls = redm[0] + logf(reds[0]);

    for (int i = tid; i < 8000; i += 256) {
        float4 v = p4[i];
        v.x -= ls; v.y -= ls; v.z -= ls; v.w -= ls;
        p4[i] = v;
    }
}

// ---------------------------------------------------------------------------
extern "C" void kernel_launch(void* const* d_in, const int* in_sizes, int n_in,
                              void* d_out, int out_size, void* d_ws, size_t ws_size,
                              hipStream_t stream)
{
    const int T = 64, B = 32, TB = T * B;  // 2048

    const int*   pos         = (const int*)d_in[0];
    const int*   word        = (const int*)d_in[1];
    const float* pos_emb_W   = (const float*)d_in[2];
    const float* word_emb_W  = (const float*)d_in[3];
    const float* w2p_W       = (const float*)d_in[4];
    const float* w2p_b       = (const float*)d_in[5];
    const float* p2w_W       = (const float*)d_in[6];
    const float* p2w_b       = (const float*)d_in[7];
    const float* p_Wih0      = (const float*)d_in[8];
    const float* p_Whh0      = (const float*)d_in[9];
    const float* p_bih0      = (const float*)d_in[10];
    const float* p_bhh0      = (const float*)d_in[11];
    const float* w_Wih0      = (const float*)d_in[12];
    const float* w_Whh0      = (const float*)d_in[13];
    const float* w_bih0      = (const float*)d_in[14];
    const float* w_bhh0      = (const float*)d_in[15];
    const float* w_Wih1      = (const float*)d_in[16];
    const float* w_Whh1      = (const float*)d_in[17];
    const float* w_bih1      = (const float*)d_in[18];
    const float* w_bhh1      = (const float*)d_in[19];
    const float* pos_proj_W  = (const float*)d_in[20];
    const float* pos_proj_b  = (const float*)d_in[21];
    const float* word_proj1W = (const float*)d_in[22];
    const float* word_proj1b = (const float*)d_in[23];
    const float* word_proj2b = (const float*)d_in[24];

    float* out   = (float*)d_out;
    float* Pout  = out;                 // [2048 x 48]
    float* Wout  = out + (size_t)TB * 48;  // [2048 x 32000]

    // workspace layout (floats)
    float* ws = (float*)d_ws;
    size_t off = 0;
    auto alloc = [&](size_t n) { float* p = ws + off; off += n; return p; };
    float* Xp    = alloc((size_t)TB * 128);
    float* Xw    = alloc((size_t)TB * 512);
    float* Ap    = alloc((size_t)TB * 1024);       // Wih_emb@p_emb + p biases
    float* Hp    = alloc((size_t)(TB + B) * 256);  // slot t+1 = h_p(t); slot 0 = zeros
    float* Hw1   = alloc((size_t)(TB + B) * 1024); // slot t+1 = h_w1(t); slot 0 = zeros
    float* E     = alloc((size_t)TB * 512);
    float* c_p   = alloc((size_t)B * 256);
    float* h_w0  = alloc((size_t)B * 1024);
    float* c_w0  = alloc((size_t)B * 1024);
    float* c_w1  = alloc((size_t)B * 1024);
    float* u     = alloc((size_t)B * 1024);
    float* v     = alloc((size_t)B * 256);
    float* hp_hh = alloc((size_t)B * 1024);
    float* w0_hh = alloc((size_t)B * 4096);
    float* w1_hh = alloc((size_t)B * 4096);

    // big A_w precompute parked in the (not-yet-written) w_out region of d_out
    float* Aw = Wout;  // [2048 x 4096] — dead before phase-2 logits overwrite it

    // zero initial states (c_p,h_w0,c_w0,c_w1 are contiguous)
    hipMemsetAsync(c_p, 0, (size_t)(B * 256 + 3 * B * 1024) * 4, stream);
    hipMemsetAsync(Hp,  0, (size_t)B * 256 * 4, stream);
    hipMemsetAsync(Hw1, 0, (size_t)B * 1024 * 4, stream);

    // phase 0: embeddings + input-projection precomputes (biases folded in)
    gather_emb<<<TB, 128, 0, stream>>>(pos, word, pos_emb_W, word_emb_W, Xp, Xw);
    gemm_generic<<<dim3(16, 64), 128, 0, stream>>>(Xp, 128, p_Wih0, 1152,
        p_bih0, p_bhh0, Ap, 1024, 1024, 128, 0, 0);
    gemm_generic<<<dim3(64, 64), 128, 0, stream>>>(Xw, 512, w_Wih0, 768,
        w_bih0, w_bhh0, Aw, 4096, 4096, 512, 0, 0);

    // phase 1: the recurrence (5 launches / step)
    for (int t = 0; t < T; ++t) {
        step_pre<<<160, 128, 0, stream>>>(t, Hw1, Hp, h_w0,
            w2p_W, w2p_b, p_Whh0, w_Whh0, w_Whh1, w_bih1, w_bhh1,
            u, hp_hh, w0_hh, w1_hh);
        // p-LSTM: gates = Ap[t] + p_Wih[:,128:] @ u + hp_hh
        lstm_cell<<<16, 128, 0, stream>>>(u, 1024, p_Wih0 + 128, 1152, 256,
            Ap + (size_t)t * 32 * 1024, 1024, hp_hh, 1024,
            Hp + (size_t)(t + 1) * 32 * 256, c_p);
        // v = tanh(p2w @ h_p(t) + b)
        gemm_generic<<<dim3(4, 1), 128, 0, stream>>>(
            Hp + (size_t)(t + 1) * 32 * 256, 256, p2w_W, 256,
            p2w_b, nullptr, v, 256, 256, 256, 1, 0);
        // w-LSTM0: gates = Aw[t] + w_Wih0[:,512:] @ v + w0_hh
        lstm_cell<<<64, 128, 0, stream>>>(v, 256, w_Wih0 + 512, 768, 1024,
            Aw + (size_t)t * 32 * 4096, 4096, w0_hh, 4096, h_w0, c_w0);
        // w-LSTM1: gates = w_Wih1 @ h_w0(t) + w1_hh (biases already in w1_hh)
        lstm_cell<<<64, 128, 0, stream>>>(h_w0, 1024, w_Wih1, 1024, 1024,
            nullptr, 0, w1_hh, 4096,
            Hw1 + (size_t)(t + 1) * 32 * 1024, c_w1);
    }

    // phase 2: batched heads
    // E = h_w1(all t) @ proj1^T + b
    gemm_generic<<<dim3(8, 64), 128, 0, stream>>>(Hw1 + 32 * 1024, 1024,
        word_proj1W, 1024, word_proj1b, nullptr, E, 512, 512, 1024, 0, 0);
    // vocab logits = E @ word_emb^T + b2  (swapped grid: consecutive blocks share W tile)
    gemm_generic<<<dim3(64, 500), 128, 0, stream>>>(E, 512, word_emb_W, 512,
        word_proj2b, nullptr, Wout, 32000, 32000, 512, 0, 1);
    logsoftmax_w<<<TB, 256, 0, stream>>>(Wout);
    // pos head
    pos_out_k<<<TB / 4, 256, 0, stream>>>(Hp + 32 * 256, pos_proj_W, pos_proj_b, Pout);
}